// Round 12
// baseline (526.281 us; speedup 1.0000x reference)
//
#include <hip/hip_runtime.h>
#include <hip/hip_bf16.h>
#include <math.h>

#define B_    2
#define NPTS_ 32768
#define T_    32768
#define P_    512
#define C_    4
#define D_    768
#define M_    (B_ * T_)   // 65536

typedef __bf16 bf16_t;
typedef __bf16 bf16x8 __attribute__((ext_vector_type(8)));
typedef __bf16 bf16x4 __attribute__((ext_vector_type(4)));
typedef float  f32x4  __attribute__((ext_vector_type(4)));

__device__ inline void gload16(const void* g, void* l) {
  __builtin_amdgcn_global_load_lds(
      (const __attribute__((address_space(1))) void*)g,
      (__attribute__((address_space(3))) void*)l, 16, 0, 0);
}

__device__ inline float gelu_exact(float x) {
  return 0.5f * x * (1.0f + erff(x * 0.70710678118654752f));
}

// order-preserving float <-> uint map (for atomicMax on floats)
__device__ inline unsigned fmap(float x) {
  unsigned u = __float_as_uint(x);
  return (u & 0x80000000u) ? ~u : (u | 0x80000000u);
}
__device__ inline float funmap(unsigned u) {
  unsigned v = (u & 0x80000000u) ? (u & 0x7FFFFFFFu) : ~u;
  return __uint_as_float(v);
}

// ===== bigprep: embed(4096) | wtrans(2304) | Wc(576) | b1b(3) | bcombo(3)
//                | seg(128) | umax zero(1536)  = 8646 blocks ==============
__global__ __launch_bounds__(256) void bigprep_kernel(
    const float4* __restrict__ latent4, const int* __restrict__ pidx,
    const float* __restrict__ w1a, const float* __restrict__ b1a,
    bf16_t* __restrict__ act1,
    const int* __restrict__ off, int* __restrict__ seg, uint4* __restrict__ umax,
    const float* __restrict__ w1b, const float* __restrict__ w2a,
    const float* __restrict__ w2b, const float* __restrict__ b1b,
    bf16_t* __restrict__ wBig, bf16_t* __restrict__ w2aTT,
    bf16_t* __restrict__ w2aBT, bf16_t* __restrict__ w2bT,
    float* __restrict__ bBig) {
  __shared__ float tile2[2][32][33];
  int bid = blockIdx.x, tid = threadIdx.x;
  if (bid < 4096) {
    // ---- embed: gather -> @w1a+b1a -> LN(1e-6) -> gelu; 4 rows/wave ----
    int wid = tid >> 6, lane = tid & 63;
    int mb = bid * 16 + wid * 4;
    int d8 = lane * 8, d4 = 512 + lane * 4;
    float bb[12], wreg[4][12];
    {
      float4 a0 = *(const float4*)(b1a + d8);
      float4 a1 = *(const float4*)(b1a + d8 + 4);
      float4 a2 = *(const float4*)(b1a + d4);
      bb[0]=a0.x; bb[1]=a0.y; bb[2]=a0.z; bb[3]=a0.w;
      bb[4]=a1.x; bb[5]=a1.y; bb[6]=a1.z; bb[7]=a1.w;
      bb[8]=a2.x; bb[9]=a2.y; bb[10]=a2.z; bb[11]=a2.w;
    }
    #pragma unroll
    for (int k = 0; k < 4; ++k) {
      const float* w = w1a + k * D_;
      float4 w0 = *(const float4*)(w + d8);
      float4 w1 = *(const float4*)(w + d8 + 4);
      float4 w2 = *(const float4*)(w + d4);
      wreg[k][0]=w0.x; wreg[k][1]=w0.y; wreg[k][2]=w0.z; wreg[k][3]=w0.w;
      wreg[k][4]=w1.x; wreg[k][5]=w1.y; wreg[k][6]=w1.z; wreg[k][7]=w1.w;
      wreg[k][8]=w2.x; wreg[k][9]=w2.y; wreg[k][10]=w2.z; wreg[k][11]=w2.w;
    }
    for (int rr = 0; rr < 4; ++rr) {
      int m = mb + rr;
      int b = m >> 15, t = m & (T_ - 1);
      float4 x = latent4[(size_t)b * NPTS_ + pidx[t]];
      float xk[4] = {x.x, x.y, x.z, x.w};
      float v[12];
      #pragma unroll
      for (int j = 0; j < 12; ++j) {
        v[j] = bb[j];
        #pragma unroll
        for (int k = 0; k < 4; ++k) v[j] += xk[k] * wreg[k][j];
      }
      float sum = 0.f, sq = 0.f;
      #pragma unroll
      for (int j = 0; j < 12; ++j) { sum += v[j]; sq += v[j]*v[j]; }
      #pragma unroll
      for (int o = 32; o > 0; o >>= 1) { sum += __shfl_xor(sum, o); sq += __shfl_xor(sq, o); }
      float mu = sum * (1.0f / D_);
      float rstd = rsqrtf(sq * (1.0f / D_) - mu * mu + 1e-6f);
      bf16x8 o8; bf16x4 o4;
      #pragma unroll
      for (int j = 0; j < 8; ++j) o8[j] = (bf16_t)gelu_exact((v[j] - mu) * rstd);
      #pragma unroll
      for (int j = 0; j < 4; ++j) o4[j] = (bf16_t)gelu_exact((v[8 + j] - mu) * rstd);
      size_t base = (size_t)m * D_;
      *(bf16x8*)(act1 + base + d8) = o8;
      *(bf16x4*)(act1 + base + d4) = o4;
    }
  } else if (bid < 6400) {
    // ---- weight transpose fp32 [k][n] -> bf16 [n][k] ----
    int r = bid - 4096;
    const float* src; bf16_t* dst;
    int which = r / 576; r -= which * 576;
    if (which == 0)      { src = w1b;             dst = wBig;  }  // w1b^T
    else if (which == 1) { src = w2a;             dst = w2aTT; }
    else if (which == 2) { src = w2a + D_ * D_;   dst = w2aBT; }
    else                 { src = w2b;             dst = w2bT;  }
    int n0 = (r % 24) * 32, k0 = (r / 24) * 32;
    int tx = tid & 31, ty = tid >> 5;
    #pragma unroll
    for (int i = 0; i < 4; ++i)
      tile2[0][ty + 8 * i][tx] = src[(size_t)(k0 + ty + 8 * i) * D_ + n0 + tx];
    __syncthreads();
    #pragma unroll
    for (int i = 0; i < 4; ++i)
      dst[(size_t)(n0 + ty + 8 * i) * D_ + k0 + tx] = (bf16_t)tile2[0][tx][ty + 8 * i];
  } else if (bid < 6976) {
    // ---- WcT[n][k] = sum_j w1b[k][j] * w2aB[j][n]  (fp32 vector GEMM) ----
    int r = bid - 6400;                 // 576 = 24(n) x 24(k)
    int n0 = (r / 24) * 32, k0 = (r % 24) * 32;
    int tx = tid & 31, ty = tid >> 5;
    float acc[4] = {0.f, 0.f, 0.f, 0.f};
    for (int j0 = 0; j0 < D_; j0 += 32) {
      __syncthreads();
      #pragma unroll
      for (int i = 0; i < 4; ++i) {
        tile2[0][ty + 8 * i][tx] = w1b[(size_t)(k0 + ty + 8 * i) * D_ + j0 + tx];
        tile2[1][ty + 8 * i][tx] = w2a[(size_t)(D_ + j0 + ty + 8 * i) * D_ + n0 + tx];
      }
      __syncthreads();
      #pragma unroll
      for (int jj = 0; jj < 32; ++jj) {
        float av = tile2[0][tx][jj];
        #pragma unroll
        for (int i = 0; i < 4; ++i)
          acc[i] += av * tile2[1][jj][ty + 8 * i];
      }
    }
    bf16_t* WcT = wBig + (size_t)D_ * D_;
    #pragma unroll
    for (int i = 0; i < 4; ++i)
      WcT[(size_t)(n0 + ty + 8 * i) * D_ + k0 + tx] = (bf16_t)acc[i];
  } else if (bid < 6979) {
    int n = (bid - 6976) * 256 + tid;
    bBig[n] = b1b[n];
  } else if (bid < 6982) {
    // bias_combo[n] = sum_k b1b[k] * w2aB[k][n]
    int n = (bid - 6979) * 256 + tid;
    float s = 0.f;
    for (int k = 0; k < D_; ++k) s += b1b[k] * w2a[(size_t)(D_ + k) * D_ + n];
    bBig[D_ + n] = s;
  } else if (bid < 7110) {
    int t = (bid - 6982) * 256 + tid;
    int lo = 0, hi = P_;
    while (lo < hi) {
      int mid = (lo + hi) >> 1;
      if (off[mid + 1] <= t) lo = mid + 1; else hi = mid;
    }
    seg[t] = lo;
  } else {
    umax[(size_t)(bid - 7110) * 256 + tid] = make_uint4(0, 0, 0, 0);
  }
}

// ---- z = funmap(ymax) @ w2aTop + b2a  (fp32 vector GEMM, 768 blocks) ----
__global__ __launch_bounds__(256) void zvec_kernel(
    const unsigned* __restrict__ ymax, const float* __restrict__ w2a,
    const float* __restrict__ b2a, float* __restrict__ z) {
  __shared__ float Aw[32][33], Bw[32][33];
  int r = blockIdx.x;                 // 768 = 32(m) x 24(n)
  int m0 = (r / 24) * 32, n0 = (r % 24) * 32;
  int tx = threadIdx.x & 31, ty = threadIdx.x >> 5;
  float acc[4] = {0.f, 0.f, 0.f, 0.f};
  for (int k0 = 0; k0 < D_; k0 += 32) {
    __syncthreads();
    #pragma unroll
    for (int i = 0; i < 4; ++i) {
      Aw[ty + 8 * i][tx] = funmap(ymax[(size_t)(m0 + ty + 8 * i) * D_ + k0 + tx]);
      Bw[ty + 8 * i][tx] = w2a[(size_t)(k0 + ty + 8 * i) * D_ + n0 + tx];
    }
    __syncthreads();
    #pragma unroll
    for (int kk = 0; kk < 32; ++kk) {
      float bv = Bw[kk][tx];
      #pragma unroll
      for (int i = 0; i < 4; ++i) acc[i] += Aw[ty + 8 * i][kk] * bv;
    }
  }
  float bav = b2a[n0 + tx];
  #pragma unroll
  for (int i = 0; i < 4; ++i)
    z[(size_t)(m0 + ty + 8 * i) * D_ + n0 + tx] = acc[i] + bav;
}

// ---- h2 = h2partial + z[seg]; LN(1e-5) + gelu -> bf16 (IN PLACE) -------
__global__ __launch_bounds__(256) void ln2_kernel(
    bf16_t* __restrict__ h2, const float* __restrict__ z,
    const int* __restrict__ seg, const float* __restrict__ g2,
    const float* __restrict__ beta2) {
  int wid = threadIdx.x >> 6, lane = threadIdx.x & 63;
  int m = blockIdx.x * 4 + wid;
  int b = m >> 15, t = m & (T_ - 1);
  int d8 = lane * 8, d4 = 512 + lane * 4;
  size_t base = (size_t)m * D_;
  const float* zrow = z + (size_t)((b << 9) + seg[t]) * D_;
  bf16x8 i8 = *(const bf16x8*)(h2 + base + d8);
  bf16x4 i4 = *(const bf16x4*)(h2 + base + d4);
  float4 z0 = *(const float4*)(zrow + d8);
  float4 z1 = *(const float4*)(zrow + d8 + 4);
  float4 z2 = *(const float4*)(zrow + d4);
  float v[12];
  #pragma unroll
  for (int j = 0; j < 8; ++j) v[j] = (float)i8[j];
  #pragma unroll
  for (int j = 0; j < 4; ++j) v[8 + j] = (float)i4[j];
  v[0]+=z0.x; v[1]+=z0.y; v[2]+=z0.z; v[3]+=z0.w;
  v[4]+=z1.x; v[5]+=z1.y; v[6]+=z1.z; v[7]+=z1.w;
  v[8]+=z2.x; v[9]+=z2.y; v[10]+=z2.z; v[11]+=z2.w;
  float sum = 0.f, sq = 0.f;
  #pragma unroll
  for (int j = 0; j < 12; ++j) { sum += v[j]; sq += v[j]*v[j]; }
  #pragma unroll
  for (int o = 32; o > 0; o >>= 1) { sum += __shfl_xor(sum, o); sq += __shfl_xor(sq, o); }
  float mu = sum * (1.0f / D_);
  float rstd = rsqrtf(sq * (1.0f / D_) - mu * mu + 1e-5f);
  float4 ga = *(const float4*)(g2 + d8);
  float4 gb = *(const float4*)(g2 + d8 + 4);
  float4 gc = *(const float4*)(g2 + d4);
  float4 ba = *(const float4*)(beta2 + d8);
  float4 bbv = *(const float4*)(beta2 + d8 + 4);
  float4 bc = *(const float4*)(beta2 + d4);
  float g[12] = {ga.x,ga.y,ga.z,ga.w, gb.x,gb.y,gb.z,gb.w, gc.x,gc.y,gc.z,gc.w};
  float be[12]= {ba.x,ba.y,ba.z,ba.w, bbv.x,bbv.y,bbv.z,bbv.w, bc.x,bc.y,bc.z,bc.w};
  bf16x8 o8; bf16x4 o4;
  #pragma unroll
  for (int j = 0; j < 8; ++j) o8[j] = (bf16_t)gelu_exact((v[j] - mu) * rstd * g[j] + be[j]);
  #pragma unroll
  for (int j = 0; j < 4; ++j) o4[j] = (bf16_t)gelu_exact((v[8+j] - mu) * rstd * g[8+j] + be[8+j]);
  *(bf16x8*)(h2 + base + d8) = o8;
  *(bf16x4*)(h2 + base + d4) = o4;
}

// ---------------- unmap rmax + pos_embed -> out fp32 -------------------
__global__ __launch_bounds__(256) void final2_kernel(
    const uint4* __restrict__ rmax, const float4* __restrict__ pe,
    float4* __restrict__ out) {
  int t = blockIdx.x * 256 + threadIdx.x;   // 196608 total
  int row = t / 192, col = t % 192;
  uint4 u = rmax[t];
  float4 p = pe[(row & (P_ - 1)) * 192 + col];
  float4 o;
  o.x = funmap(u.x) + p.x; o.y = funmap(u.y) + p.y;
  o.z = funmap(u.z) + p.z; o.w = funmap(u.w) + p.w;
  out[t] = o;
}

// ===== 256x256 4-phase MFMA GEMM, swapped operands ======================
// MODE 0: bias?+store. MODE 1: bias+store fp32 + fused segmax.
// MODE 2: combined N=1536; bx<3 -> segmax only (no store); bx>=3 -> store
//         bf16 at col n-768.
#define STAGE_A(P2, KTG)                                                     \
  { _Pragma("unroll")                                                        \
    for (int h = 0; h < 2; ++h) {                                            \
      _Pragma("unroll")                                                      \
      for (int ps = 0; ps < 2; ++ps) {                                       \
        int c = ps * 512 + wid * 64 + lane;                                  \
        int rw = c >> 3;                                                     \
        int cs = (c & 7) ^ (rw & 7);                                         \
        gload16(A + (size_t)(m0 + h * 128 + rw) * 768 + (KTG) + cs * 8,      \
                lds + (P2) * 65536 + h * 16384 + ps * 8192 + wid * 1024);    \
      } } }

#define STAGE_B(P2, KTG)                                                     \
  { _Pragma("unroll")                                                        \
    for (int h = 0; h < 2; ++h) {                                            \
      _Pragma("unroll")                                                      \
      for (int ps = 0; ps < 2; ++ps) {                                       \
        int c = ps * 512 + wid * 64 + lane;                                  \
        int rw = c >> 3;                                                     \
        int cs = (c & 7) ^ (rw & 7);                                         \
        gload16(BT + (size_t)(n0 + h * 128 + rw) * 768 + (KTG) + cs * 8,     \
                lds + (P2) * 65536 + 32768 + h * 16384 + ps * 8192 + wid * 1024); \
      } } }

#define READ_AF0(BASE)                                                       \
  { _Pragma("unroll")                                                        \
    for (int i = 0; i < 4; ++i) {                                            \
      _Pragma("unroll")                                                      \
      for (int s = 0; s < 2; ++s) {                                          \
        int row = i * 16 + lr;                                               \
        int ch = (s * 4 + hi) ^ cx;                                          \
        af0[i][s] = *(const bf16x8*)((BASE) + wm * 16384 + row * 128 + ch * 16); \
      } } }

#define READ_BF0(BASE)                                                       \
  { _Pragma("unroll")                                                        \
    for (int jb = 0; jb < 2; ++jb) {                                         \
      _Pragma("unroll")                                                      \
      for (int s = 0; s < 2; ++s) {                                          \
        int nrow = wn * 64 + jb * 16 + lr;                                   \
        int ch = (s * 4 + hi) ^ cx;                                          \
        bf0[jb][s] = *(const bf16x8*)((BASE) + 32768 + (nrow >> 7) * 16384 + \
                                      (nrow & 127) * 128 + ch * 16);         \
      } } }

template <int MODE, bool HASBIAS, typename OutT>
__global__ __launch_bounds__(512, 1) void gemm256_kernel(
    const bf16_t* __restrict__ A, const bf16_t* __restrict__ BT,
    const float* __restrict__ bias, OutT* __restrict__ C,
    const int* __restrict__ seg, unsigned* __restrict__ gmax) {
  constexpr int NT = 12;                 // K = 768 / 64
  __shared__ __align__(16) char lds[131072];
  __shared__ int segm[256];
  int tid = threadIdx.x;
  int wid = tid >> 6, lane = tid & 63;
  int lr = lane & 15, hi = lane >> 4;
  int wm = wid >> 2, wn = wid & 3;

  int gx = gridDim.x;
  int nb = gx * gridDim.y;
  int bid = blockIdx.y * gx + blockIdx.x;
  int w = ((nb & 7) == 0) ? ((bid & 7) * (nb >> 3) + (bid >> 3)) : bid;
  int bx = w % gx, by = w / gx;
  int n0 = bx * 256, m0 = by * 256;

  if (MODE != 0) { if (tid < 256) segm[tid] = seg[(m0 + tid) & (T_ - 1)]; }

  f32x4 acc[8][4] = {};
  bf16x8 af0[4][2], af1[4][2], bf0[2][2], bf1[2][2];
  int cx = lr & 7;

  STAGE_A(0, 0); STAGE_B(0, 0);
  STAGE_A(1, 64); STAGE_B(1, 64);
  asm volatile("s_waitcnt vmcnt(8)" ::: "memory");
  __builtin_amdgcn_s_barrier();
  READ_AF0(lds); READ_BF0(lds);

  for (int j = 0; j < NT; ++j) {
    const char* base  = lds + (j & 1) * 65536;
    const char* baseN = lds + ((j & 1) ^ 1) * 65536;

    // ---- P0: read af1(j); MFMA Q00 ----
    #pragma unroll
    for (int i = 0; i < 4; ++i)
      #pragma unroll
      for (int s = 0; s < 2; ++s) {
        int row = 64 + i * 16 + lr;
        int ch = (s * 4 + hi) ^ cx;
        af1[i][s] = *(const bf16x8*)(base + wm * 16384 + row * 128 + ch * 16);
      }
    __builtin_amdgcn_s_setprio(1);
    #pragma unroll
    for (int i = 0; i < 4; ++i)
      #pragma unroll
      for (int jb = 0; jb < 2; ++jb)
        #pragma unroll
        for (int s = 0; s < 2; ++s)
          acc[i][jb] = __builtin_amdgcn_mfma_f32_16x16x32_bf16(bf0[jb][s], af0[i][s], acc[i][jb], 0, 0, 0);
    __builtin_amdgcn_s_setprio(0);
    __builtin_amdgcn_s_barrier();

    // ---- P1: read bf1(j); MFMA Q10 ----
    #pragma unroll
    for (int jb = 0; jb < 2; ++jb)
      #pragma unroll
      for (int s = 0; s < 2; ++s) {
        int nrow = wn * 64 + 32 + jb * 16 + lr;
        int ch = (s * 4 + hi) ^ cx;
        bf1[jb][s] = *(const bf16x8*)(base + 32768 + (nrow >> 7) * 16384 +
                                      (nrow & 127) * 128 + ch * 16);
      }
    __builtin_amdgcn_s_setprio(1);
    #pragma unroll
    for (int i = 0; i < 4; ++i)
      #pragma unroll
      for (int jb = 0; jb < 2; ++jb)
        #pragma unroll
        for (int s = 0; s < 2; ++s)
          acc[4 + i][jb] = __builtin_amdgcn_mfma_f32_16x16x32_bf16(bf0[jb][s], af1[i][s], acc[4 + i][jb], 0, 0, 0);
    __builtin_amdgcn_s_setprio(0);
    __builtin_amdgcn_s_barrier();

    // ---- P2: stage A(j+2); MFMA Q01 ----
    if (j + 2 < NT) STAGE_A(j & 1, (j + 2) * 64);
    __builtin_amdgcn_s_setprio(1);
    #pragma unroll
    for (int i = 0; i < 4; ++i)
      #pragma unroll
      for (int jb = 0; jb < 2; ++jb)
        #pragma unroll
        for (int s = 0; s < 2; ++s)
          acc[i][2 + jb] = __builtin_amdgcn_mfma_f32_16x16x32_bf16(bf1[jb][s], af0[i][s], acc[i][2 + jb], 0, 0, 0);
    __builtin_amdgcn_s_setprio(0);

    // ---- P3: gate tile j+1; read af0/bf0(j+1); stage B(j+2); MFMA Q11 ----
    if (j + 1 < NT) {
      if (j + 2 < NT) asm volatile("s_waitcnt vmcnt(4)" ::: "memory");
      else            asm volatile("s_waitcnt vmcnt(0)" ::: "memory");
      __builtin_amdgcn_s_barrier();
      READ_AF0(baseN); READ_BF0(baseN);
      if (j + 2 < NT) STAGE_B(j & 1, (j + 2) * 64);
    }
    __builtin_amdgcn_s_setprio(1);
    #pragma unroll
    for (int i = 0; i < 4; ++i)
      #pragma unroll
      for (int jb = 0; jb < 2; ++jb)
        #pragma unroll
        for (int s = 0; s < 2; ++s)
          acc[4 + i][2 + jb] = __builtin_amdgcn_mfma_f32_16x16x32_bf16(bf1[jb][s], af1[i][s], acc[4 + i][2 + jb], 0, 0, 0);
    __builtin_amdgcn_s_setprio(0);
    __builtin_amdgcn_s_barrier();
  }

  // ---- epilogue ----------------------------------------------------------
  f32x4 bvv[4];
  #pragma unroll
  for (int jb = 0; jb < 4; ++jb) {
    if (HASBIAS) {
      const float* bp = bias + n0 + wn * 64 + jb * 16 + hi * 4;
      bvv[jb][0] = bp[0]; bvv[jb][1] = bp[1]; bvv[jb][2] = bp[2]; bvv[jb][3] = bp[3];
    } else {
      bvv[jb][0] = bvv[jb][1] = bvv[jb][2] = bvv[jb][3] = 0.f;
    }
  }

  bool is_h = (MODE == 2) && (bx < 3);
  if (!is_h) {
    int nc0 = (MODE == 2) ? n0 - 768 : n0;
    #pragma unroll
    for (int i = 0; i < 8; ++i) {
      size_t ro = (size_t)(m0 + wm * 128 + i * 16 + lr) * 768 + (nc0 + wn * 64 + hi * 4);
      #pragma unroll
      for (int jb = 0; jb < 4; ++jb) {
        f32x4 v = acc[i][jb] + bvv[jb];
        if constexpr (sizeof(OutT) == 4) {
          *reinterpret_cast<f32x4*>(C + ro + jb * 16) = v;
        } else {
          bf16x4 o;
          #pragma unroll
          for (int r = 0; r < 4; ++r) o[r] = (bf16_t)v[r];
          *reinterpret_cast<bf16x4*>(C + ro + jb * 16) = o;
        }
      }
    }
  }

  if (MODE == 1 || is_h) {
    unsigned* smax = reinterpret_cast<unsigned*>(lds);
    __builtin_amdgcn_s_barrier();        // LDS tiles dead for all waves
    int sb = segm[0];
    int zb = (m0 >> 15) << 9;            // batch * 512
    for (int q = tid; q < 16 * 256; q += 512) smax[q] = 0u;
    __syncthreads();

    int lrow = wm * 128 + lr;
    #pragma unroll
    for (int jb = 0; jb < 4; ++jb) {
      int nl = wn * 64 + jb * 16 + hi * 4;
      f32x4 run = acc[0][jb] + bvv[jb];
      int ps = segm[lrow];
      #pragma unroll
      for (int i = 1; i < 8; ++i) {
        int cs2 = segm[lrow + i * 16];
        f32x4 v = acc[i][jb] + bvv[jb];
        if (cs2 != ps) {
          #pragma unroll
          for (int r = 0; r < 4; ++r)
            atomicMax(&smax[(ps - sb) * 256 + nl + r], fmap(run[r]));
          run = v; ps = cs2;
        } else {
          #pragma unroll
          for (int r = 0; r < 4; ++r) run[r] = fmaxf(run[r], v[r]);
        }
      }
      #pragma unroll
      for (int r = 0; r < 4; ++r)
        atomicMax(&smax[(ps - sb) * 256 + nl + r], fmap(run[r]));
    }
    __syncthreads();

    int nseg = segm[255] - sb + 1;
    int mlo = m0 & (T_ - 1);
    bool strad_lo = (mlo != 0) && (seg[mlo - 1] == sb);
    bool strad_hi = (mlo + 256 < T_) && (seg[mlo + 256] == segm[255]);
    for (int q = tid; q < nseg * 256; q += 512) {
      int sl = q >> 8, nl2 = q & 255;
      unsigned val = smax[q];
      unsigned* dst = &gmax[(size_t)(zb + sb + sl) * 768 + n0 + nl2];
      bool bdry = (sl == 0 && strad_lo) || (sl == nseg - 1 && strad_hi);
      if (bdry) atomicMax(dst, val);
      else      *dst = val;               // exclusive owner of this segment
    }
  }
}

extern "C" void kernel_launch(void* const* d_in, const int* in_sizes, int n_in,
                              void* d_out, int out_size, void* d_ws, size_t ws_size,
                              hipStream_t stream) {
  const float* latent       = (const float*)d_in[0];
  const int*   patch_index  = (const int*)d_in[1];
  const int*   patch_offset = (const int*)d_in[2];
  const float* pos_embed    = (const float*)d_in[3];
  const float* w1a  = (const float*)d_in[4];
  const float* b1a  = (const float*)d_in[5];
  const float* w1b  = (const float*)d_in[6];
  const float* b1b  = (const float*)d_in[7];
  const float* w2a  = (const float*)d_in[8];
  const float* b2a  = (const float*)d_in[9];
  const float* g2   = (const float*)d_in[10];
  const float* beta2= (const float*)d_in[11];
  const float* w2b  = (const float*)d_in[12];
  const float* b2b  = (const float*)d_in[13];

  float* out_f   = (float*)d_out;
  float* raw_out = out_f + (size_t)B_ * P_ * D_;

  char* ws = (char*)d_ws;
  size_t off = 0;
  auto take = [&](size_t bytes) {
    off = (off + 255) & ~(size_t)255;
    char* p = ws + off;
    off += bytes;
    return p;
  };
  int*      seg   = (int*)     take((size_t)T_ * 4);
  bf16_t*   wBig  = (bf16_t*)  take((size_t)2 * D_ * D_ * 2);  // [w1bT | WcT]
  bf16_t*   w2aTT = (bf16_t*)  take((size_t)D_ * D_ * 2);
  bf16_t*   w2aBT = (bf16_t*)  take((size_t)D_ * D_ * 2);
  bf16_t*   w2bT  = (bf16_t*)  take((size_t)D_ * D_ * 2);
  float*    bBig  = (float*)   take((size_t)2 * D_ * 4);       // [b1b | bcombo]
  float*    zbuf  = (float*)   take((size_t)B_ * P_ * D_ * 4);
  unsigned* umax  = (unsigned*)take((size_t)2 * B_ * P_ * D_ * 4);  // ymax|rmax
  unsigned* ymax  = umax;
  unsigned* rmax  = umax + (size_t)B_ * P_ * D_;
  bf16_t*   bufY  = (bf16_t*)  take((size_t)M_ * D_ * 2);      // h2partial/act2
  size_t needX = (size_t)M_ * D_ * 2;
  size_t offX  = (off + 255) & ~(size_t)255;
  bf16_t* bufX;                                                 // act1
  if (offX + needX <= ws_size) {
    bufX = (bf16_t*)take(needX);
  } else {
    bufX = (bf16_t*)raw_out;  // act1 dead after K2, before K6 writes raw
  }

  // K1: embed | 4x transpose | Wc | b1b | bcombo | seg | umax zero
  bigprep_kernel<<<8646, 256, 0, stream>>>(
      (const float4*)latent, patch_index, w1a, b1a, bufX,
      patch_offset, seg, (uint4*)umax,
      w1b, w2a, w2b, b1b,
      wBig, w2aTT, w2aBT, w2bT, bBig);

  // K2: combined  [h | h2partial] = act1 @ [w1bT | WcT] + bBig
  //     bx<3: fused y-segmax only (h never stored); bx>=3: store h2 -> bufY
  gemm256_kernel<2, true, bf16_t><<<dim3(6, M_/256), 512, 0, stream>>>(
      bufX, wBig, bBig, bufY, seg, ymax);

  // K3: z = funmap(ymax) @ w2a_top + b2a   (fp32 vector GEMM)
  zvec_kernel<<<768, 256, 0, stream>>>(ymax, w2a, b2a, zbuf);

  // K4: act2 = gelu(LN(h2partial + z[seg]) * g2 + beta2)   (in place)
  ln2_kernel<<<M_ / 4, 256, 0, stream>>>(bufY, zbuf, seg, g2, beta2);

  // K5: raw = act2 @ w2b + b2b (fp32 -> d_out); fused r-segmax -> rmax
  gemm256_kernel<1, true, float><<<dim3(3, M_/256), 512, 0, stream>>>(
      bufY, w2bT, b2b, raw_out, seg, rmax);

  // K6: out = unmap(rmax) + pos_embed
  final2_kernel<<<768, 256, 0, stream>>>(
      (const uint4*)rmax, (const float4*)pos_embed, (float4*)out_f);
}

// Round 13
// 484.175 us; speedup vs baseline: 1.0870x; 1.0870x over previous
//
#include <hip/hip_runtime.h>
#include <hip/hip_bf16.h>
#include <math.h>

#define B_    2
#define NPTS_ 32768
#define T_    32768
#define P_    512
#define C_    4
#define D_    768
#define M_    (B_ * T_)   // 65536

typedef __bf16 bf16_t;
typedef __bf16 bf16x8 __attribute__((ext_vector_type(8)));
typedef __bf16 bf16x4 __attribute__((ext_vector_type(4)));
typedef float  f32x4  __attribute__((ext_vector_type(4)));

__device__ inline void gload16(const void* g, void* l) {
  __builtin_amdgcn_global_load_lds(
      (const __attribute__((address_space(1))) void*)g,
      (__attribute__((address_space(3))) void*)l, 16, 0, 0);
}

__device__ inline float gelu_exact(float x) {
  return 0.5f * x * (1.0f + erff(x * 0.70710678118654752f));
}

// order-preserving float <-> uint map (for atomicMax on floats)
__device__ inline unsigned fmap(float x) {
  unsigned u = __float_as_uint(x);
  return (u & 0x80000000u) ? ~u : (u | 0x80000000u);
}
__device__ inline float funmap(unsigned u) {
  unsigned v = (u & 0x80000000u) ? (u & 0x7FFFFFFFu) : ~u;
  return __uint_as_float(v);
}

// ===== bigprep: embed(4096) | wtrans(1728) | seg(128) | umax zero(1536) ==
__global__ __launch_bounds__(256) void bigprep_kernel(
    const float4* __restrict__ latent4, const int* __restrict__ pidx,
    const float* __restrict__ w1a, const float* __restrict__ b1a,
    bf16_t* __restrict__ act1,
    const int* __restrict__ off, int* __restrict__ seg, uint4* __restrict__ umax,
    const float* __restrict__ w1b, const float* __restrict__ w2a,
    const float* __restrict__ w2b,
    bf16_t* __restrict__ w1bT, bf16_t* __restrict__ w2aBT,
    bf16_t* __restrict__ w2bT) {
  int bid = blockIdx.x, tid = threadIdx.x;
  if (bid < 4096) {
    // ---- embed: gather -> @w1a+b1a -> LN(1e-6) -> gelu; 4 rows/wave ----
    int wid = tid >> 6, lane = tid & 63;
    int mb = bid * 16 + wid * 4;
    int d8 = lane * 8, d4 = 512 + lane * 4;
    float bb[12], wreg[4][12];
    {
      float4 a0 = *(const float4*)(b1a + d8);
      float4 a1 = *(const float4*)(b1a + d8 + 4);
      float4 a2 = *(const float4*)(b1a + d4);
      bb[0]=a0.x; bb[1]=a0.y; bb[2]=a0.z; bb[3]=a0.w;
      bb[4]=a1.x; bb[5]=a1.y; bb[6]=a1.z; bb[7]=a1.w;
      bb[8]=a2.x; bb[9]=a2.y; bb[10]=a2.z; bb[11]=a2.w;
    }
    #pragma unroll
    for (int k = 0; k < 4; ++k) {
      const float* w = w1a + k * D_;
      float4 w0 = *(const float4*)(w + d8);
      float4 w1 = *(const float4*)(w + d8 + 4);
      float4 w2 = *(const float4*)(w + d4);
      wreg[k][0]=w0.x; wreg[k][1]=w0.y; wreg[k][2]=w0.z; wreg[k][3]=w0.w;
      wreg[k][4]=w1.x; wreg[k][5]=w1.y; wreg[k][6]=w1.z; wreg[k][7]=w1.w;
      wreg[k][8]=w2.x; wreg[k][9]=w2.y; wreg[k][10]=w2.z; wreg[k][11]=w2.w;
    }
    for (int rr = 0; rr < 4; ++rr) {
      int m = mb + rr;
      int b = m >> 15, t = m & (T_ - 1);
      float4 x = latent4[(size_t)b * NPTS_ + pidx[t]];
      float xk[4] = {x.x, x.y, x.z, x.w};
      float v[12];
      #pragma unroll
      for (int j = 0; j < 12; ++j) {
        v[j] = bb[j];
        #pragma unroll
        for (int k = 0; k < 4; ++k) v[j] += xk[k] * wreg[k][j];
      }
      float sum = 0.f, sq = 0.f;
      #pragma unroll
      for (int j = 0; j < 12; ++j) { sum += v[j]; sq += v[j]*v[j]; }
      #pragma unroll
      for (int o = 32; o > 0; o >>= 1) { sum += __shfl_xor(sum, o); sq += __shfl_xor(sq, o); }
      float mu = sum * (1.0f / D_);
      float rstd = rsqrtf(sq * (1.0f / D_) - mu * mu + 1e-6f);
      bf16x8 o8; bf16x4 o4;
      #pragma unroll
      for (int j = 0; j < 8; ++j) o8[j] = (bf16_t)gelu_exact((v[j] - mu) * rstd);
      #pragma unroll
      for (int j = 0; j < 4; ++j) o4[j] = (bf16_t)gelu_exact((v[8 + j] - mu) * rstd);
      size_t base = (size_t)m * D_;
      *(bf16x8*)(act1 + base + d8) = o8;
      *(bf16x4*)(act1 + base + d4) = o4;
    }
  } else if (bid < 5824) {
    __shared__ float tile[32][33];
    int r = bid - 4096;
    const float* src; bf16_t* dst;
    int which = r / 576; r -= which * 576;
    if (which == 0)      { src = w1b;             dst = w1bT;  }
    else if (which == 1) { src = w2a + D_ * D_;   dst = w2aBT; }
    else                 { src = w2b;             dst = w2bT;  }
    int n0 = (r % 24) * 32, k0 = (r / 24) * 32;
    int tx = tid & 31, ty = tid >> 5;
    #pragma unroll
    for (int i = 0; i < 4; ++i)
      tile[ty + 8 * i][tx] = src[(size_t)(k0 + ty + 8 * i) * D_ + n0 + tx];
    __syncthreads();
    #pragma unroll
    for (int i = 0; i < 4; ++i)
      dst[(size_t)(n0 + ty + 8 * i) * D_ + k0 + tx] = (bf16_t)tile[tx][ty + 8 * i];
  } else if (bid < 5952) {
    int t = (bid - 5824) * 256 + tid;
    int lo = 0, hi = P_;
    while (lo < hi) {
      int mid = (lo + hi) >> 1;
      if (off[mid + 1] <= t) lo = mid + 1; else hi = mid;
    }
    seg[t] = lo;
  } else {
    umax[(size_t)(bid - 5952) * 256 + tid] = make_uint4(0, 0, 0, 0);
  }
}

// ---- z = funmap(ymax) @ w2aTop + b2a  (fp32 vector GEMM, 768 blocks) ----
__global__ __launch_bounds__(256) void zvec_kernel(
    const unsigned* __restrict__ ymax, const float* __restrict__ w2a,
    const float* __restrict__ b2a, float* __restrict__ z) {
  __shared__ float Aw[32][33], Bw[32][33];
  int r = blockIdx.x;                 // 768 = 32(m) x 24(n)
  int m0 = (r / 24) * 32, n0 = (r % 24) * 32;
  int tx = threadIdx.x & 31, ty = threadIdx.x >> 5;
  float acc[4] = {0.f, 0.f, 0.f, 0.f};
  for (int k0 = 0; k0 < D_; k0 += 32) {
    __syncthreads();
    #pragma unroll
    for (int i = 0; i < 4; ++i) {
      Aw[ty + 8 * i][tx] = funmap(ymax[(size_t)(m0 + ty + 8 * i) * D_ + k0 + tx]);
      Bw[ty + 8 * i][tx] = w2a[(size_t)(k0 + ty + 8 * i) * D_ + n0 + tx];
    }
    __syncthreads();
    #pragma unroll
    for (int kk = 0; kk < 32; ++kk) {
      float bv = Bw[kk][tx];
      #pragma unroll
      for (int i = 0; i < 4; ++i) acc[i] += Aw[ty + 8 * i][kk] * bv;
    }
  }
  float bav = b2a[n0 + tx];
  #pragma unroll
  for (int i = 0; i < 4; ++i)
    z[(size_t)(m0 + ty + 8 * i) * D_ + n0 + tx] = acc[i] + bav;
}

// ---- h2 = h2partial + z[seg]; LN(1e-5, g2, beta2) + gelu -> bf16 -------
__global__ __launch_bounds__(256) void ln2_kernel(
    const bf16_t* __restrict__ h2pre, const float* __restrict__ z,
    const int* __restrict__ seg, const float* __restrict__ g2,
    const float* __restrict__ beta2, bf16_t* __restrict__ act2) {
  int wid = threadIdx.x >> 6, lane = threadIdx.x & 63;
  int m = blockIdx.x * 4 + wid;
  int b = m >> 15, t = m & (T_ - 1);
  int d8 = lane * 8, d4 = 512 + lane * 4;
  size_t base = (size_t)m * D_;
  const float* zrow = z + (size_t)((b << 9) + seg[t]) * D_;
  bf16x8 i8 = *(const bf16x8*)(h2pre + base + d8);
  bf16x4 i4 = *(const bf16x4*)(h2pre + base + d4);
  float4 z0 = *(const float4*)(zrow + d8);
  float4 z1 = *(const float4*)(zrow + d8 + 4);
  float4 z2 = *(const float4*)(zrow + d4);
  float v[12];
  #pragma unroll
  for (int j = 0; j < 8; ++j) v[j] = (float)i8[j];
  #pragma unroll
  for (int j = 0; j < 4; ++j) v[8 + j] = (float)i4[j];
  v[0]+=z0.x; v[1]+=z0.y; v[2]+=z0.z; v[3]+=z0.w;
  v[4]+=z1.x; v[5]+=z1.y; v[6]+=z1.z; v[7]+=z1.w;
  v[8]+=z2.x; v[9]+=z2.y; v[10]+=z2.z; v[11]+=z2.w;
  float sum = 0.f, sq = 0.f;
  #pragma unroll
  for (int j = 0; j < 12; ++j) { sum += v[j]; sq += v[j]*v[j]; }
  #pragma unroll
  for (int o = 32; o > 0; o >>= 1) { sum += __shfl_xor(sum, o); sq += __shfl_xor(sq, o); }
  float mu = sum * (1.0f / D_);
  float rstd = rsqrtf(sq * (1.0f / D_) - mu * mu + 1e-5f);
  float4 ga = *(const float4*)(g2 + d8);
  float4 gb = *(const float4*)(g2 + d8 + 4);
  float4 gc = *(const float4*)(g2 + d4);
  float4 ba = *(const float4*)(beta2 + d8);
  float4 bbv = *(const float4*)(beta2 + d8 + 4);
  float4 bc = *(const float4*)(beta2 + d4);
  float g[12] = {ga.x,ga.y,ga.z,ga.w, gb.x,gb.y,gb.z,gb.w, gc.x,gc.y,gc.z,gc.w};
  float be[12]= {ba.x,ba.y,ba.z,ba.w, bbv.x,bbv.y,bbv.z,bbv.w, bc.x,bc.y,bc.z,bc.w};
  bf16x8 o8; bf16x4 o4;
  #pragma unroll
  for (int j = 0; j < 8; ++j) o8[j] = (bf16_t)gelu_exact((v[j] - mu) * rstd * g[j] + be[j]);
  #pragma unroll
  for (int j = 0; j < 4; ++j) o4[j] = (bf16_t)gelu_exact((v[8+j] - mu) * rstd * g[8+j] + be[8+j]);
  *(bf16x8*)(act2 + base + d8) = o8;
  *(bf16x4*)(act2 + base + d4) = o4;
}

// ---------------- unmap rmax + pos_embed -> out fp32 -------------------
__global__ __launch_bounds__(256) void final2_kernel(
    const uint4* __restrict__ rmax, const float4* __restrict__ pe,
    float4* __restrict__ out) {
  int t = blockIdx.x * 256 + threadIdx.x;   // 196608 total
  int row = t / 192, col = t % 192;
  uint4 u = rmax[t];
  float4 p = pe[(row & (P_ - 1)) * 192 + col];
  float4 o;
  o.x = funmap(u.x) + p.x; o.y = funmap(u.y) + p.y;
  o.z = funmap(u.z) + p.z; o.w = funmap(u.w) + p.w;
  out[t] = o;
}

// ===== 256x256 8-wave 4-phase MFMA GEMM (R6 verbatim: best measured) ====
#define STAGE_A(P2, KTG)                                                     \
  { _Pragma("unroll")                                                        \
    for (int h = 0; h < 2; ++h) {                                            \
      _Pragma("unroll")                                                      \
      for (int ps = 0; ps < 2; ++ps) {                                       \
        int c = ps * 512 + wid * 64 + lane;                                  \
        int rw = c >> 3;                                                     \
        int cs = (c & 7) ^ (rw & 7);                                         \
        gload16(A + (size_t)(m0 + h * 128 + rw) * 768 + (KTG) + cs * 8,      \
                lds + (P2) * 65536 + h * 16384 + ps * 8192 + wid * 1024);    \
      } } }

#define STAGE_B(P2, KTG)                                                     \
  { _Pragma("unroll")                                                        \
    for (int h = 0; h < 2; ++h) {                                            \
      _Pragma("unroll")                                                      \
      for (int ps = 0; ps < 2; ++ps) {                                       \
        int c = ps * 512 + wid * 64 + lane;                                  \
        int rw = c >> 3;                                                     \
        int cs = (c & 7) ^ (rw & 7);                                         \
        gload16(BT + (size_t)(n0 + h * 128 + rw) * 768 + (KTG) + cs * 8,     \
                lds + (P2) * 65536 + 32768 + h * 16384 + ps * 8192 + wid * 1024); \
      } } }

#define READ_AF0(BASE)                                                       \
  { _Pragma("unroll")                                                        \
    for (int i = 0; i < 4; ++i) {                                            \
      _Pragma("unroll")                                                      \
      for (int s = 0; s < 2; ++s) {                                          \
        int row = i * 16 + lr;                                               \
        int ch = (s * 4 + hi) ^ cx;                                          \
        af0[i][s] = *(const bf16x8*)((BASE) + wm * 16384 + row * 128 + ch * 16); \
      } } }

#define READ_BF0(BASE)                                                       \
  { _Pragma("unroll")                                                        \
    for (int jb = 0; jb < 2; ++jb) {                                         \
      _Pragma("unroll")                                                      \
      for (int s = 0; s < 2; ++s) {                                          \
        int nrow = wn * 64 + jb * 16 + lr;                                   \
        int ch = (s * 4 + hi) ^ cx;                                          \
        bf0[jb][s] = *(const bf16x8*)((BASE) + 32768 + (nrow >> 7) * 16384 + \
                                      (nrow & 127) * 128 + ch * 16);         \
      } } }

template <bool HASBIAS, bool SEGMAX, typename OutT>
__global__ __launch_bounds__(512, 1) void gemm256_kernel(
    const bf16_t* __restrict__ A, const bf16_t* __restrict__ BT,
    const float* __restrict__ bias, OutT* __restrict__ C,
    const int* __restrict__ seg, unsigned* __restrict__ gmax) {
  constexpr int NT = 12;                 // 768 / 64
  __shared__ __align__(16) char lds[131072];
  __shared__ int segm[256];
  int tid = threadIdx.x;
  int wid = tid >> 6, lane = tid & 63;
  int lr = lane & 15, hi = lane >> 4;
  int wm = wid >> 2, wn = wid & 3;

  int gx = gridDim.x;                    // 3
  int nb = gx * gridDim.y;
  int bid = blockIdx.y * gx + blockIdx.x;
  int w = ((nb & 7) == 0) ? ((bid & 7) * (nb >> 3) + (bid >> 3)) : bid;
  int bx = w % gx, by = w / gx;
  int n0 = bx * 256, m0 = by * 256;

  if (SEGMAX) { if (tid < 256) segm[tid] = seg[(m0 + tid) & (T_ - 1)]; }

  f32x4 acc[8][4] = {};
  bf16x8 af0[4][2], af1[4][2], bf0[2][2], bf1[2][2];
  int cx = lr & 7;

  // prologue: stage K-tiles 0 and 1; gate tile 0; pre-read af0/bf0 of tile 0
  STAGE_A(0, 0); STAGE_B(0, 0);
  STAGE_A(1, 64); STAGE_B(1, 64);
  asm volatile("s_waitcnt vmcnt(8)" ::: "memory");
  __builtin_amdgcn_s_barrier();
  READ_AF0(lds); READ_BF0(lds);

  for (int j = 0; j < NT; ++j) {
    const char* base  = lds + (j & 1) * 65536;
    const char* baseN = lds + ((j & 1) ^ 1) * 65536;

    // ---- P0: read af1(j); MFMA Q00 ----
    #pragma unroll
    for (int i = 0; i < 4; ++i)
      #pragma unroll
      for (int s = 0; s < 2; ++s) {
        int row = 64 + i * 16 + lr;
        int ch = (s * 4 + hi) ^ cx;
        af1[i][s] = *(const bf16x8*)(base + wm * 16384 + row * 128 + ch * 16);
      }
    __builtin_amdgcn_s_setprio(1);
    #pragma unroll
    for (int i = 0; i < 4; ++i)
      #pragma unroll
      for (int jb = 0; jb < 2; ++jb)
        #pragma unroll
        for (int s = 0; s < 2; ++s)
          acc[i][jb] = __builtin_amdgcn_mfma_f32_16x16x32_bf16(af0[i][s], bf0[jb][s], acc[i][jb], 0, 0, 0);
    __builtin_amdgcn_s_setprio(0);
    __builtin_amdgcn_s_barrier();

    // ---- P1: read bf1(j); MFMA Q10 ----
    #pragma unroll
    for (int jb = 0; jb < 2; ++jb)
      #pragma unroll
      for (int s = 0; s < 2; ++s) {
        int nrow = wn * 64 + 32 + jb * 16 + lr;
        int ch = (s * 4 + hi) ^ cx;
        bf1[jb][s] = *(const bf16x8*)(base + 32768 + (nrow >> 7) * 16384 +
                                      (nrow & 127) * 128 + ch * 16);
      }
    __builtin_amdgcn_s_setprio(1);
    #pragma unroll
    for (int i = 0; i < 4; ++i)
      #pragma unroll
      for (int jb = 0; jb < 2; ++jb)
        #pragma unroll
        for (int s = 0; s < 2; ++s)
          acc[4 + i][jb] = __builtin_amdgcn_mfma_f32_16x16x32_bf16(af1[i][s], bf0[jb][s], acc[4 + i][jb], 0, 0, 0);
    __builtin_amdgcn_s_setprio(0);
    __builtin_amdgcn_s_barrier();

    // ---- P2: stage A(j+2); MFMA Q01 ----
    if (j + 2 < NT) STAGE_A(j & 1, (j + 2) * 64);
    __builtin_amdgcn_s_setprio(1);
    #pragma unroll
    for (int i = 0; i < 4; ++i)
      #pragma unroll
      for (int jb = 0; jb < 2; ++jb)
        #pragma unroll
        for (int s = 0; s < 2; ++s)
          acc[i][2 + jb] = __builtin_amdgcn_mfma_f32_16x16x32_bf16(af0[i][s], bf1[jb][s], acc[i][2 + jb], 0, 0, 0);
    __builtin_amdgcn_s_setprio(0);

    // ---- P3: gate tile j+1; read af0/bf0(j+1); stage B(j+2); MFMA Q11 ----
    if (j + 1 < NT) {
      if (j + 2 < NT) asm volatile("s_waitcnt vmcnt(4)" ::: "memory");
      else            asm volatile("s_waitcnt vmcnt(0)" ::: "memory");
      __builtin_amdgcn_s_barrier();
      READ_AF0(baseN); READ_BF0(baseN);
      if (j + 2 < NT) STAGE_B(j & 1, (j + 2) * 64);
    }
    __builtin_amdgcn_s_setprio(1);
    #pragma unroll
    for (int i = 0; i < 4; ++i)
      #pragma unroll
      for (int jb = 0; jb < 2; ++jb)
        #pragma unroll
        for (int s = 0; s < 2; ++s)
          acc[4 + i][2 + jb] = __builtin_amdgcn_mfma_f32_16x16x32_bf16(af1[i][s], bf1[jb][s], acc[4 + i][2 + jb], 0, 0, 0);
    __builtin_amdgcn_s_setprio(0);
    __builtin_amdgcn_s_barrier();
  }

  // ---- epilogue: bias + C store + fused segmax ----
  unsigned* smax = reinterpret_cast<unsigned*>(lds);
  int sb = 0, zb = 0;
  if (SEGMAX) {
    sb = segm[0];
    zb = (m0 >> 15) << 9;                // batch * 512
    for (int q = tid; q < 16 * 256; q += 512) smax[q] = 0u;
    __syncthreads();
  }

  #pragma unroll
  for (int jn = 0; jn < 4; ++jn) {
    int nl = wn * 64 + jn * 16 + lr;
    int n = n0 + nl;
    float bv = HASBIAS ? bias[n] : 0.f;
    #pragma unroll
    for (int i = 0; i < 8; ++i) {
      int rb = wm * 128 + i * 16 + hi * 4;
      float vv[4];
      #pragma unroll
      for (int r = 0; r < 4; ++r) {
        vv[r] = acc[i][jn][r] + bv;
        C[(size_t)(m0 + rb + r) * 768 + n] = (OutT)vv[r];
      }
      if (SEGMAX) {
        int sA = segm[rb] - sb, sB = segm[rb + 3] - sb;
        if (sA == sB) {
          float mx = fmaxf(fmaxf(vv[0], vv[1]), fmaxf(vv[2], vv[3]));
          atomicMax(&smax[sA * 256 + nl], fmap(mx));
        } else {
          #pragma unroll
          for (int r = 0; r < 4; ++r)
            atomicMax(&smax[(segm[rb + r] - sb) * 256 + nl], fmap(vv[r]));
        }
      }
    }
  }

  if (SEGMAX) {
    __syncthreads();
    int nseg = segm[255] - sb + 1;
    int mlo = m0 & (T_ - 1);
    bool strad_lo = (mlo != 0) && (seg[mlo - 1] == sb);
    bool strad_hi = (mlo + 256 < T_) && (seg[mlo + 256] == segm[255]);
    for (int q = tid; q < nseg * 256; q += 512) {
      int sl = q >> 8, nl2 = q & 255;
      unsigned val = smax[q];
      unsigned* dst = &gmax[(size_t)(zb + sb + sl) * 768 + n0 + nl2];
      bool bdry = (sl == 0 && strad_lo) || (sl == nseg - 1 && strad_hi);
      if (bdry) atomicMax(dst, val);
      else      *dst = val;               // exclusive owner of this segment
    }
  }
}

extern "C" void kernel_launch(void* const* d_in, const int* in_sizes, int n_in,
                              void* d_out, int out_size, void* d_ws, size_t ws_size,
                              hipStream_t stream) {
  const float* latent       = (const float*)d_in[0];
  const int*   patch_index  = (const int*)d_in[1];
  const int*   patch_offset = (const int*)d_in[2];
  const float* pos_embed    = (const float*)d_in[3];
  const float* w1a  = (const float*)d_in[4];
  const float* b1a  = (const float*)d_in[5];
  const float* w1b  = (const float*)d_in[6];
  const float* b1b  = (const float*)d_in[7];
  const float* w2a  = (const float*)d_in[8];
  const float* b2a  = (const float*)d_in[9];
  const float* g2   = (const float*)d_in[10];
  const float* beta2= (const float*)d_in[11];
  const float* w2b  = (const float*)d_in[12];
  const float* b2b  = (const float*)d_in[13];

  float* out_f   = (float*)d_out;
  float* raw_out = out_f + (size_t)B_ * P_ * D_;

  char* ws = (char*)d_ws;
  size_t off = 0;
  auto take = [&](size_t bytes) {
    off = (off + 255) & ~(size_t)255;
    char* p = ws + off;
    off += bytes;
    return p;
  };
  int*      seg   = (int*)     take((size_t)T_ * 4);
  bf16_t*   w1bT  = (bf16_t*)  take((size_t)D_ * D_ * 2);
  bf16_t*   w2aBT = (bf16_t*)  take((size_t)D_ * D_ * 2);
  bf16_t*   w2bT  = (bf16_t*)  take((size_t)D_ * D_ * 2);
  float*    zbuf  = (float*)   take((size_t)B_ * P_ * D_ * 4);
  unsigned* umax  = (unsigned*)take((size_t)2 * B_ * P_ * D_ * 4);  // ymax|rmax
  unsigned* ymax  = umax;
  unsigned* rmax  = umax + (size_t)B_ * P_ * D_;
  bf16_t*   bufY  = (bf16_t*)  take((size_t)M_ * D_ * 2);
  size_t needX = (size_t)M_ * D_ * 2;
  size_t offX  = (off + 255) & ~(size_t)255;
  bf16_t* bufX;
  if (offX + needX <= ws_size) {
    bufX = (bf16_t*)take(needX);
  } else {
    bufX = (bf16_t*)raw_out;  // dead before G4 overwrites with real raw
  }

  // K1: embed | 3x weight transpose | seg | umax zero
  bigprep_kernel<<<7488, 256, 0, stream>>>(
      (const float4*)latent, patch_index, w1a, b1a, bufX,
      patch_offset, seg, (uint4*)umax,
      w1b, w2a, w2b, w1bT, w2aBT, w2bT);

  // K2: h = act1 @ w1b + b1b; fused y-segmax -> ymax
  gemm256_kernel<true, true, bf16_t><<<dim3(3, M_/256), 512, 0, stream>>>(
      bufX, w1bT, b1b, bufY, seg, ymax);

  // K3: z = funmap(ymax) @ w2a_top + b2a  (fp32 vector GEMM)
  zvec_kernel<<<768, 256, 0, stream>>>(ymax, w2a, b2a, zbuf);

  // K4: h2partial = h @ w2a_bot  (plain, no bias)
  gemm256_kernel<false, false, bf16_t><<<dim3(3, M_/256), 512, 0, stream>>>(
      bufY, w2aBT, nullptr, bufX, nullptr, nullptr);

  // K5: act2 = gelu(LN(h2partial + z[seg]) * g2 + beta2)
  ln2_kernel<<<M_ / 4, 256, 0, stream>>>(bufX, zbuf, seg, g2, beta2, bufY);

  // K6: raw = act2 @ w2b + b2b (fp32 -> d_out); fused r-segmax -> rmax
  gemm256_kernel<true, true, float><<<dim3(3, M_/256), 512, 0, stream>>>(
      bufY, w2bT, b2b, raw_out, seg, rmax);

  // K7: out = unmap(rmax) + pos_embed
  final2_kernel<<<768, 256, 0, stream>>>(
      (const uint4*)rmax, (const float4*)pos_embed, (float4*)out_f);
}

// Round 14
// 452.266 us; speedup vs baseline: 1.1637x; 1.0706x over previous
//
#include <hip/hip_runtime.h>
#include <hip/hip_bf16.h>
#include <math.h>

#define B_    2
#define NPTS_ 32768
#define T_    32768
#define P_    512
#define C_    4
#define D_    768
#define M_    (B_ * T_)   // 65536

typedef __bf16 bf16_t;
typedef __bf16 bf16x8 __attribute__((ext_vector_type(8)));
typedef __bf16 bf16x4 __attribute__((ext_vector_type(4)));
typedef float  f32x4  __attribute__((ext_vector_type(4)));

__device__ inline void gload16(const void* g, void* l) {
  __builtin_amdgcn_global_load_lds(
      (const __attribute__((address_space(1))) void*)g,
      (__attribute__((address_space(3))) void*)l, 16, 0, 0);
}

__device__ inline float gelu_exact(float x) {
  return 0.5f * x * (1.0f + erff(x * 0.70710678118654752f));
}

// order-preserving float <-> uint map (for atomicMax on floats)
__device__ inline unsigned fmap(float x) {
  unsigned u = __float_as_uint(x);
  return (u & 0x80000000u) ? ~u : (u | 0x80000000u);
}
__device__ inline float funmap(unsigned u) {
  unsigned v = (u & 0x80000000u) ? (u & 0x7FFFFFFFu) : ~u;
  return __uint_as_float(v);
}

// ---- fused prep: 4x weight transpose + seg binary search + umax zero ----
__global__ __launch_bounds__(256) void prep_kernel(
    const int* __restrict__ off, int* __restrict__ seg, uint4* __restrict__ umax,
    const float* __restrict__ w1b, const float* __restrict__ w2a,
    const float* __restrict__ w2b,
    bf16_t* __restrict__ w1bT, bf16_t* __restrict__ w2aTT,
    bf16_t* __restrict__ w2aBT, bf16_t* __restrict__ w2bT) {
  __shared__ float tile[32][33];
  int bid = blockIdx.x, tid = threadIdx.x;
  if (bid < 2304) {
    const float* src; bf16_t* dst;
    int which = bid / 576, r = bid - which * 576;
    if (which == 0)      { src = w1b;             dst = w1bT;  }
    else if (which == 1) { src = w2a;             dst = w2aTT; }
    else if (which == 2) { src = w2a + D_ * D_;   dst = w2aBT; }
    else                 { src = w2b;             dst = w2bT;  }
    int n0 = (r % 24) * 32, k0 = (r / 24) * 32;
    int tx = tid & 31, ty = tid >> 5;
    #pragma unroll
    for (int i = 0; i < 4; ++i)
      tile[ty + 8 * i][tx] = src[(size_t)(k0 + ty + 8 * i) * D_ + n0 + tx];
    __syncthreads();
    #pragma unroll
    for (int i = 0; i < 4; ++i)
      dst[(size_t)(n0 + ty + 8 * i) * D_ + k0 + tx] = (bf16_t)tile[tx][ty + 8 * i];
  } else if (bid < 2432) {
    int t = (bid - 2304) * 256 + tid;
    int lo = 0, hi = P_;
    while (lo < hi) {
      int mid = (lo + hi) >> 1;
      if (off[mid + 1] <= t) lo = mid + 1; else hi = mid;
    }
    seg[t] = lo;
  } else {
    umax[(size_t)(bid - 2432) * 256 + tid] = make_uint4(0, 0, 0, 0);
  }
}

// ---------------- unmap ymax -> bf16 y ---------------------------------
__global__ __launch_bounds__(256) void yconv_kernel(
    const uint4* __restrict__ ymax, bf16_t* __restrict__ y) {
  int t = blockIdx.x * 256 + threadIdx.x;   // 196608 total
  uint4 u = ymax[t];
  bf16x4 o;
  o[0] = (bf16_t)funmap(u.x); o[1] = (bf16_t)funmap(u.y);
  o[2] = (bf16_t)funmap(u.z); o[3] = (bf16_t)funmap(u.w);
  *(bf16x4*)(y + (size_t)t * 4) = o;
}

// ---------------- unmap rmax + pos_embed -> out fp32 -------------------
__global__ __launch_bounds__(256) void final2_kernel(
    const uint4* __restrict__ rmax, const float4* __restrict__ pe,
    float4* __restrict__ out) {
  int t = blockIdx.x * 256 + threadIdx.x;   // 196608 total
  int row = t / 192, col = t % 192;         // 768/4 = 192
  uint4 u = rmax[t];
  float4 p = pe[(row & (P_ - 1)) * 192 + col];
  float4 o;
  o.x = funmap(u.x) + p.x; o.y = funmap(u.y) + p.y;
  o.z = funmap(u.z) + p.z; o.w = funmap(u.w) + p.w;
  out[t] = o;
}

// -------- fused: gather latent -> @w1a + b1a -> LN(1e-6) -> gelu -> bf16
__global__ __launch_bounds__(256) void embed_kernel(
    const float4* __restrict__ latent4, const int* __restrict__ pidx,
    const float* __restrict__ w1a, const float* __restrict__ b1a,
    bf16_t* __restrict__ act1) {
  int wid = threadIdx.x >> 6, lane = threadIdx.x & 63;
  int m = blockIdx.x * 4 + wid;
  int b = m >> 15, t = m & (T_ - 1);
  float4 x = latent4[(size_t)b * NPTS_ + pidx[t]];
  int d8 = lane * 8, d4 = 512 + lane * 4;
  float v[12];
  {
    float4 a0 = *(const float4*)(b1a + d8);
    float4 a1 = *(const float4*)(b1a + d8 + 4);
    float4 a2 = *(const float4*)(b1a + d4);
    v[0]=a0.x; v[1]=a0.y; v[2]=a0.z; v[3]=a0.w;
    v[4]=a1.x; v[5]=a1.y; v[6]=a1.z; v[7]=a1.w;
    v[8]=a2.x; v[9]=a2.y; v[10]=a2.z; v[11]=a2.w;
  }
  float xk[4] = {x.x, x.y, x.z, x.w};
  #pragma unroll
  for (int k = 0; k < 4; ++k) {
    const float* w = w1a + k * D_;
    float4 w0 = *(const float4*)(w + d8);
    float4 w1 = *(const float4*)(w + d8 + 4);
    float4 w2 = *(const float4*)(w + d4);
    float f = xk[k];
    v[0] += f*w0.x; v[1] += f*w0.y; v[2] += f*w0.z; v[3] += f*w0.w;
    v[4] += f*w1.x; v[5] += f*w1.y; v[6] += f*w1.z; v[7] += f*w1.w;
    v[8] += f*w2.x; v[9] += f*w2.y; v[10]+= f*w2.z; v[11]+= f*w2.w;
  }
  float sum = 0.f, sq = 0.f;
  #pragma unroll
  for (int j = 0; j < 12; ++j) { sum += v[j]; sq += v[j]*v[j]; }
  #pragma unroll
  for (int o = 32; o > 0; o >>= 1) { sum += __shfl_xor(sum, o); sq += __shfl_xor(sq, o); }
  float mu = sum * (1.0f / D_);
  float rstd = rsqrtf(sq * (1.0f / D_) - mu * mu + 1e-6f);
  bf16x8 o8; bf16x4 o4;
  #pragma unroll
  for (int j = 0; j < 8; ++j) o8[j] = (bf16_t)gelu_exact((v[j] - mu) * rstd);
  #pragma unroll
  for (int j = 0; j < 4; ++j) o4[j] = (bf16_t)gelu_exact((v[8 + j] - mu) * rstd);
  size_t base = (size_t)m * D_;
  *(bf16x8*)(act1 + base + d8) = o8;
  *(bf16x4*)(act1 + base + d4) = o4;
}

// ---- h2 = h2partial + z[seg]; LN(1e-5, g2, beta2) + gelu -> bf16 -------
__global__ __launch_bounds__(256) void ln2_kernel(
    const bf16_t* __restrict__ h2pre, const float* __restrict__ z,
    const int* __restrict__ seg, const float* __restrict__ g2,
    const float* __restrict__ beta2, bf16_t* __restrict__ act2) {
  int wid = threadIdx.x >> 6, lane = threadIdx.x & 63;
  int m = blockIdx.x * 4 + wid;
  int b = m >> 15, t = m & (T_ - 1);
  int d8 = lane * 8, d4 = 512 + lane * 4;
  size_t base = (size_t)m * D_;
  const float* zrow = z + (size_t)((b << 9) + seg[t]) * D_;
  bf16x8 i8 = *(const bf16x8*)(h2pre + base + d8);
  bf16x4 i4 = *(const bf16x4*)(h2pre + base + d4);
  float4 z0 = *(const float4*)(zrow + d8);
  float4 z1 = *(const float4*)(zrow + d8 + 4);
  float4 z2 = *(const float4*)(zrow + d4);
  float v[12];
  #pragma unroll
  for (int j = 0; j < 8; ++j) v[j] = (float)i8[j];
  #pragma unroll
  for (int j = 0; j < 4; ++j) v[8 + j] = (float)i4[j];
  v[0]+=z0.x; v[1]+=z0.y; v[2]+=z0.z; v[3]+=z0.w;
  v[4]+=z1.x; v[5]+=z1.y; v[6]+=z1.z; v[7]+=z1.w;
  v[8]+=z2.x; v[9]+=z2.y; v[10]+=z2.z; v[11]+=z2.w;
  float sum = 0.f, sq = 0.f;
  #pragma unroll
  for (int j = 0; j < 12; ++j) { sum += v[j]; sq += v[j]*v[j]; }
  #pragma unroll
  for (int o = 32; o > 0; o >>= 1) { sum += __shfl_xor(sum, o); sq += __shfl_xor(sq, o); }
  float mu = sum * (1.0f / D_);
  float rstd = rsqrtf(sq * (1.0f / D_) - mu * mu + 1e-5f);
  float4 ga = *(const float4*)(g2 + d8);
  float4 gb = *(const float4*)(g2 + d8 + 4);
  float4 gc = *(const float4*)(g2 + d4);
  float4 ba = *(const float4*)(beta2 + d8);
  float4 bb = *(const float4*)(beta2 + d8 + 4);
  float4 bc = *(const float4*)(beta2 + d4);
  float g[12] = {ga.x,ga.y,ga.z,ga.w, gb.x,gb.y,gb.z,gb.w, gc.x,gc.y,gc.z,gc.w};
  float be[12]= {ba.x,ba.y,ba.z,ba.w, bb.x,bb.y,bb.z,bb.w, bc.x,bc.y,bc.z,bc.w};
  bf16x8 o8; bf16x4 o4;
  #pragma unroll
  for (int j = 0; j < 8; ++j) o8[j] = (bf16_t)gelu_exact((v[j] - mu) * rstd * g[j] + be[j]);
  #pragma unroll
  for (int j = 0; j < 4; ++j) o4[j] = (bf16_t)gelu_exact((v[8+j] - mu) * rstd * g[8+j] + be[8+j]);
  *(bf16x8*)(act2 + base + d8) = o8;
  *(bf16x4*)(act2 + base + d4) = o4;
}

// ===== 256x256 8-phase MFMA GEMM (T2+T3+T4+T5), K = N = 768 =============
#define STAGE_A(P2, KTG)                                                     \
  { _Pragma("unroll")                                                        \
    for (int h = 0; h < 2; ++h) {                                            \
      _Pragma("unroll")                                                      \
      for (int ps = 0; ps < 2; ++ps) {                                       \
        int c = ps * 512 + wid * 64 + lane;                                  \
        int rw = c >> 3;                                                     \
        int cs = (c & 7) ^ (rw & 7);                                         \
        gload16(A + (size_t)(m0 + h * 128 + rw) * 768 + (KTG) + cs * 8,      \
                lds + (P2) * 65536 + h * 16384 + ps * 8192 + wid * 1024);    \
      } } }

#define STAGE_B(P2, KTG)                                                     \
  { _Pragma("unroll")                                                        \
    for (int h = 0; h < 2; ++h) {                                            \
      _Pragma("unroll")                                                      \
      for (int ps = 0; ps < 2; ++ps) {                                       \
        int c = ps * 512 + wid * 64 + lane;                                  \
        int rw = c >> 3;                                                     \
        int cs = (c & 7) ^ (rw & 7);                                         \
        gload16(BT + (size_t)(n0 + h * 128 + rw) * 768 + (KTG) + cs * 8,     \
                lds + (P2) * 65536 + 32768 + h * 16384 + ps * 8192 + wid * 1024); \
      } } }

template <bool HASBIAS, bool SEGMAX, typename OutT>
__global__ __launch_bounds__(512, 1) void gemm256_kernel(
    const bf16_t* __restrict__ A, const bf16_t* __restrict__ BT,
    const float* __restrict__ bias, OutT* __restrict__ C,
    const int* __restrict__ seg, unsigned* __restrict__ gmax) {
  constexpr int NT = 12;                 // 768 / 64
  __shared__ __align__(16) char lds[131072];
  __shared__ int segm[256];
  int tid = threadIdx.x;
  int wid = tid >> 6, lane = tid & 63;
  int lr = lane & 15, hi = lane >> 4;
  int wm = wid >> 2, wn = wid & 3;

  int gx = gridDim.x;                    // 3
  int nb = gx * gridDim.y;
  int bid = blockIdx.y * gx + blockIdx.x;
  int w = ((nb & 7) == 0) ? ((bid & 7) * (nb >> 3) + (bid >> 3)) : bid;
  int bx = w % gx, by = w / gx;
  int n0 = bx * 256, m0 = by * 256;

  if (SEGMAX) { if (tid < 256) segm[tid] = seg[(m0 + tid) & (T_ - 1)]; }

  f32x4 acc[8][4] = {};
  bf16x8 af0[4][2], af1[4][2], bf0[2][2], bf1[2][2];
  int cx = lr & 7;

  // prologue: stage K-tiles 0 (parity 0) and 1 (parity 1); 16 loads/thread
  STAGE_A(0, 0); STAGE_B(0, 0);
  STAGE_A(1, 64); STAGE_B(1, 64);

  for (int j = 0; j < NT; ++j) {
    int p = j & 1;
    const char* base = lds + p * 65536;
    // ---- q0: vmcnt gate + ds_read(A mq0, B nq0) + MFMA(mq0,nq0) ----
    if (j < NT - 1) asm volatile("s_waitcnt vmcnt(8)" ::: "memory");
    else            asm volatile("s_waitcnt vmcnt(0)" ::: "memory");
    __builtin_amdgcn_s_barrier();
    #pragma unroll
    for (int i = 0; i < 4; ++i)
      #pragma unroll
      for (int s = 0; s < 2; ++s) {
        int row = i * 16 + lr;
        int ch = (s * 4 + hi) ^ cx;
        af0[i][s] = *(const bf16x8*)(base + wm * 16384 + row * 128 + ch * 16);
      }
    #pragma unroll
    for (int jb = 0; jb < 2; ++jb)
      #pragma unroll
      for (int s = 0; s < 2; ++s) {
        int nrow = wn * 64 + jb * 16 + lr;
        int ch = (s * 4 + hi) ^ cx;
        bf0[jb][s] = *(const bf16x8*)(base + 32768 + (nrow >> 7) * 16384 +
                                      (nrow & 127) * 128 + ch * 16);
      }
    __builtin_amdgcn_s_barrier();
    __builtin_amdgcn_s_setprio(1);
    #pragma unroll
    for (int i = 0; i < 4; ++i)
      #pragma unroll
      for (int jb = 0; jb < 2; ++jb)
        #pragma unroll
        for (int s = 0; s < 2; ++s)
          acc[i][jb] = __builtin_amdgcn_mfma_f32_16x16x32_bf16(af0[i][s], bf0[jb][s], acc[i][jb], 0, 0, 0);
    __builtin_amdgcn_s_setprio(0);
    __builtin_amdgcn_s_barrier();

    // ---- q1: ds_read(A mq1) + MFMA(mq1,nq0) ----
    #pragma unroll
    for (int i = 0; i < 4; ++i)
      #pragma unroll
      for (int s = 0; s < 2; ++s) {
        int row = 64 + i * 16 + lr;
        int ch = (s * 4 + hi) ^ cx;
        af1[i][s] = *(const bf16x8*)(base + wm * 16384 + row * 128 + ch * 16);
      }
    __builtin_amdgcn_s_barrier();
    __builtin_amdgcn_s_setprio(1);
    #pragma unroll
    for (int i = 0; i < 4; ++i)
      #pragma unroll
      for (int jb = 0; jb < 2; ++jb)
        #pragma unroll
        for (int s = 0; s < 2; ++s)
          acc[4 + i][jb] = __builtin_amdgcn_mfma_f32_16x16x32_bf16(af1[i][s], bf0[jb][s], acc[4 + i][jb], 0, 0, 0);
    __builtin_amdgcn_s_setprio(0);
    __builtin_amdgcn_s_barrier();

    // ---- q2: ds_read(B nq1) + stage A[j+2] + MFMA(mq0,nq1) ----
    #pragma unroll
    for (int jb = 0; jb < 2; ++jb)
      #pragma unroll
      for (int s = 0; s < 2; ++s) {
        int nrow = wn * 64 + 32 + jb * 16 + lr;
        int ch = (s * 4 + hi) ^ cx;
        bf1[jb][s] = *(const bf16x8*)(base + 32768 + (nrow >> 7) * 16384 +
                                      (nrow & 127) * 128 + ch * 16);
      }
    if (j + 2 < NT) STAGE_A(p, (j + 2) * 64);
    __builtin_amdgcn_s_barrier();
    __builtin_amdgcn_s_setprio(1);
    #pragma unroll
    for (int i = 0; i < 4; ++i)
      #pragma unroll
      for (int jb = 0; jb < 2; ++jb)
        #pragma unroll
        for (int s = 0; s < 2; ++s)
          acc[i][2 + jb] = __builtin_amdgcn_mfma_f32_16x16x32_bf16(af0[i][s], bf1[jb][s], acc[i][2 + jb], 0, 0, 0);
    __builtin_amdgcn_s_setprio(0);
    __builtin_amdgcn_s_barrier();

    // ---- q3: stage B[j+2] + MFMA(mq1,nq1) ----
    if (j + 2 < NT) STAGE_B(p, (j + 2) * 64);
    __builtin_amdgcn_s_barrier();
    __builtin_amdgcn_s_setprio(1);
    #pragma unroll
    for (int i = 0; i < 4; ++i)
      #pragma unroll
      for (int jb = 0; jb < 2; ++jb)
        #pragma unroll
        for (int s = 0; s < 2; ++s)
          acc[4 + i][2 + jb] = __builtin_amdgcn_mfma_f32_16x16x32_bf16(af1[i][s], bf1[jb][s], acc[4 + i][2 + jb], 0, 0, 0);
    __builtin_amdgcn_s_setprio(0);
    // q3 end barrier is next iteration's q0 barrier (or epilogue barrier)
  }

  // ---- epilogue: bias + C store + fused segmax ----
  unsigned* smax = reinterpret_cast<unsigned*>(lds);
  int sb = 0, zb = 0;
  if (SEGMAX) {
    __builtin_amdgcn_s_barrier();        // LDS tiles dead for all waves
    sb = segm[0];
    zb = (m0 >> 15) << 9;                // batch * 512
    for (int q = tid; q < 16 * 256; q += 512) smax[q] = 0u;
    __syncthreads();
  }

  #pragma unroll
  for (int jn = 0; jn < 4; ++jn) {
    int nl = wn * 64 + jn * 16 + lr;
    int n = n0 + nl;
    float bv = HASBIAS ? bias[n] : 0.f;
    #pragma unroll
    for (int i = 0; i < 8; ++i) {
      int rb = wm * 128 + i * 16 + hi * 4;
      float vv[4];
      #pragma unroll
      for (int r = 0; r < 4; ++r) {
        vv[r] = acc[i][jn][r] + bv;
        C[(size_t)(m0 + rb + r) * 768 + n] = (OutT)vv[r];
      }
      if (SEGMAX) {
        int sA = segm[rb] - sb, sB = segm[rb + 3] - sb;
        if (sA == sB) {
          float mx = fmaxf(fmaxf(vv[0], vv[1]), fmaxf(vv[2], vv[3]));
          atomicMax(&smax[sA * 256 + nl], fmap(mx));
        } else {
          #pragma unroll
          for (int r = 0; r < 4; ++r)
            atomicMax(&smax[(segm[rb + r] - sb) * 256 + nl], fmap(vv[r]));
        }
      }
    }
  }

  if (SEGMAX) {
    __syncthreads();
    int nseg = segm[255] - sb + 1;
    int mlo = m0 & (T_ - 1);
    // does first/last segment straddle this block's row range?
    bool strad_lo = (mlo != 0) && (seg[(mlo - 1)] == sb);
    bool strad_hi = (mlo + 256 < T_) && (seg[(mlo + 256)] == segm[255]);
    for (int q = tid; q < nseg * 256; q += 512) {
      int sl = q >> 8, nl2 = q & 255;
      unsigned val = smax[q];
      unsigned* dst = &gmax[(size_t)(zb + sb + sl) * 768 + n0 + nl2];
      bool bdry = (sl == 0 && strad_lo) || (sl == nseg - 1 && strad_hi);
      if (bdry) atomicMax(dst, val);
      else      *dst = val;               // exclusive owner of this segment
    }
  }
}

extern "C" void kernel_launch(void* const* d_in, const int* in_sizes, int n_in,
                              void* d_out, int out_size, void* d_ws, size_t ws_size,
                              hipStream_t stream) {
  const float* latent       = (const float*)d_in[0];
  const int*   patch_index  = (const int*)d_in[1];
  const int*   patch_offset = (const int*)d_in[2];
  const float* pos_embed    = (const float*)d_in[3];
  const float* w1a  = (const float*)d_in[4];
  const float* b1a  = (const float*)d_in[5];
  const float* w1b  = (const float*)d_in[6];
  const float* b1b  = (const float*)d_in[7];
  const float* w2a  = (const float*)d_in[8];
  const float* b2a  = (const float*)d_in[9];
  const float* g2   = (const float*)d_in[10];
  const float* beta2= (const float*)d_in[11];
  const float* w2b  = (const float*)d_in[12];
  const float* b2b  = (const float*)d_in[13];

  float* out_f   = (float*)d_out;
  float* raw_out = out_f + (size_t)B_ * P_ * D_;

  char* ws = (char*)d_ws;
  size_t off = 0;
  auto take = [&](size_t bytes) {
    off = (off + 255) & ~(size_t)255;
    char* p = ws + off;
    off += bytes;
    return p;
  };
  int*      seg   = (int*)     take((size_t)T_ * 4);
  bf16_t*   w1bT  = (bf16_t*)  take((size_t)D_ * D_ * 2);
  bf16_t*   w2aTT = (bf16_t*)  take((size_t)D_ * D_ * 2);
  bf16_t*   w2aBT = (bf16_t*)  take((size_t)D_ * D_ * 2);
  bf16_t*   w2bT  = (bf16_t*)  take((size_t)D_ * D_ * 2);
  bf16_t*   ybuf  = (bf16_t*)  take((size_t)B_ * P_ * D_ * 2);
  float*    zbuf  = (float*)   take((size_t)B_ * P_ * D_ * 4);
  unsigned* umax  = (unsigned*)take((size_t)2 * B_ * P_ * D_ * 4);  // ymax|rmax
  unsigned* ymax  = umax;
  unsigned* rmax  = umax + (size_t)B_ * P_ * D_;
  bf16_t*   bufY  = (bf16_t*)  take((size_t)M_ * D_ * 2);
  size_t needX = (size_t)M_ * D_ * 2;
  size_t offX  = (off + 255) & ~(size_t)255;
  bf16_t* bufX;
  if (offX + needX <= ws_size) {
    bufX = (bf16_t*)take(needX);
  } else {
    bufX = (bf16_t*)raw_out;  // dead before gemm3 overwrites with real raw
  }

  // fused prep: 4 weight transposes + seg + umax zero
  prep_kernel<<<3968, 256, 0, stream>>>(patch_offset, seg, (uint4*)umax,
                                        w1b, w2a, w2b, w1bT, w2aTT, w2aBT, w2bT);

  // act1 = gelu(LN(latent[pidx] @ w1a + b1a))
  embed_kernel<<<M_ / 4, 256, 0, stream>>>((const float4*)latent, patch_index, w1a, b1a, bufX);

  // h = act1 @ w1b + b1b; fused y = segmax(h) -> ymax
  gemm256_kernel<true, true, bf16_t><<<dim3(3, M_/256), 512, 0, stream>>>(
      bufX, w1bT, b1b, bufY, seg, ymax);

  // y bf16
  yconv_kernel<<<(B_ * P_ * D_) / (4 * 256), 256, 0, stream>>>((const uint4*)ymax, ybuf);

  // z = y @ w2a_top + b2a   (1024 x 768 x 768, fp32 out)
  gemm256_kernel<true, false, float><<<dim3(3, (B_*P_)/256), 512, 0, stream>>>(
      ybuf, w2aTT, b2a, zbuf, nullptr, nullptr);

  // h2partial = h @ w2a_bot   (no bias; z added in ln2)
  gemm256_kernel<false, false, bf16_t><<<dim3(3, M_/256), 512, 0, stream>>>(
      bufY, w2aBT, nullptr, bufX, nullptr, nullptr);

  // act2 = gelu(LN(h2partial + z[seg]) * g2 + beta2)
  ln2_kernel<<<M_ / 4, 256, 0, stream>>>(bufX, zbuf, seg, g2, beta2, bufY);

  // raw = act2 @ w2b + b2b (fp32 -> d_out); fused segmax -> rmax
  gemm256_kernel<true, true, float><<<dim3(3, M_/256), 512, 0, stream>>>(
      bufY, w2bT, b2b, raw_out, seg, rmax);

  // out = unmap(rmax) + pos_embed
  final2_kernel<<<(B_ * P_ * D_) / (4 * 256), 256, 0, stream>>>(
      (const uint4*)rmax, (const float4*)pos_embed, (float4*)out_f);
}